// Round 6
// baseline (266.705 us; speedup 1.0000x reference)
//
#include <hip/hip_runtime.h>
#include <stdint.h>
#include <stddef.h>

#define M_DIM 2048
#define N_DIM 11008
#define K_DIM 4096
#define BM 128
#define BN 256
#define BK 64
#define NT (K_DIM / BK)   // 64
#define NBM (M_DIM / BM)  // 16
#define NBN (N_DIM / BN)  // 43
#define GRID (NBM * NBN)  // 688 (divisible by 8 -> XCD swizzle bijective)

typedef __attribute__((ext_vector_type(4))) float f32x4;
typedef __attribute__((ext_vector_type(4))) float f4;
typedef __attribute__((ext_vector_type(4))) int i4;
typedef __attribute__((ext_vector_type(8))) __bf16 bf16x8;
typedef __attribute__((ext_vector_type(8))) unsigned short us8;

#define VMCNT0() asm volatile("s_waitcnt vmcnt(0)" ::: "memory")
#define FENCE() asm volatile("" ::: "memory")
#define BARRIER()                 \
  do {                            \
    FENCE();                      \
    __builtin_amdgcn_s_barrier(); \
    FENCE();                      \
  } while (0)

// round-to-nearest-even fp32 -> bf16
__device__ inline unsigned short f2bf(float f) {
  unsigned u = __builtin_bit_cast(unsigned, f);
  u += 0x7fffu + ((u >> 16) & 1u);
  return (unsigned short)(u >> 16);
}

__device__ inline void gload_lds16(const void* g, void* l) {
  __builtin_amdgcn_global_load_lds((const __attribute__((address_space(1))) void*)g,
                                   (__attribute__((address_space(3))) void*)l, 16, 0, 0);
}

// ---------------- conversion kernels ----------------

__global__ void __launch_bounds__(256) cvt_x_kernel(const float* __restrict__ x,
                                                    us8* __restrict__ xb, int n8) {
  int i = blockIdx.x * 256 + threadIdx.x;
  if (i >= n8) return;
  const f4* src = (const f4*)x;
  f4 a = src[2 * i];
  f4 b = src[2 * i + 1];
  us8 o;
  o[0] = f2bf(a[0]); o[1] = f2bf(a[1]); o[2] = f2bf(a[2]); o[3] = f2bf(a[3]);
  o[4] = f2bf(b[0]); o[5] = f2bf(b[1]); o[6] = f2bf(b[2]); o[7] = f2bf(b[3]);
  xb[i] = o;
}

// W_q arrives as int32 per element; int8-range values are exact in bf16.
__global__ void __launch_bounds__(256) cvt_w_kernel(const int* __restrict__ w,
                                                    us8* __restrict__ wb, int n16) {
  int i = blockIdx.x * 256 + threadIdx.x;
  if (i >= n16) return;
  const i4* src = (const i4*)w + 4 * (size_t)i;
  i4 v0 = src[0], v1 = src[1], v2 = src[2], v3 = src[3];
  us8 lo, hi;
  lo[0] = f2bf((float)v0[0]); lo[1] = f2bf((float)v0[1]);
  lo[2] = f2bf((float)v0[2]); lo[3] = f2bf((float)v0[3]);
  lo[4] = f2bf((float)v1[0]); lo[5] = f2bf((float)v1[1]);
  lo[6] = f2bf((float)v1[2]); lo[7] = f2bf((float)v1[3]);
  hi[0] = f2bf((float)v2[0]); hi[1] = f2bf((float)v2[1]);
  hi[2] = f2bf((float)v2[2]); hi[3] = f2bf((float)v2[3]);
  hi[4] = f2bf((float)v3[0]); hi[5] = f2bf((float)v3[1]);
  hi[6] = f2bf((float)v3[2]); hi[7] = f2bf((float)v3[3]);
  wb[2 * (size_t)i] = lo;
  wb[2 * (size_t)i + 1] = hi;
}

// ---- register-pipelined GEMM: 1 barrier + 1 vmcnt per K-tile, LDS||MFMA overlap ----
// 128x256 tile, BK=64, 8 waves = 4 N-strips x 2 K-halves; wave computes 128x64 over K=32.
// Clusters per tile: C0 = a0(rows0-63) x b, C1 = a1(rows64-127) x b (16 MFMA each).
// Skewed loop: iter t = { vmcnt0; barrier; STAGE6(t+2); read a0(t+1); C1(t);
//                         read b(t+1), a1(t+1); C0(t+1) }.
// lgkm pending ledger at each cluster: C1(t): [a1(t)=4, a0(t+1)=4] -> lgkmcnt(4);
// C0(t+1): [a0=4(waited), b=4, a1=4] -> lgkmcnt(4). Compiler emits these counted waits;
// ds_reads retire UNDER the other cluster's MFMAs (separate pipes).
// vmcnt(0) per iter is counted-equivalent: only S(t+1) outstanding there (S(t+2) issues
// after), with one full iteration (~1500cy > 900cy HBM) of issue->wait slack.
// Buffer safety (3 bufs, 1 barrier/tile): reads of buf (t-1)%3 are lgkm-drained before
// their MFMAs, which precede barrier(t); STAGE6 into that buf is after barrier(t).

#define STAGE2(g0, g1, dst)          \
  do {                               \
    gload_lds16((g0), (dst));        \
    gload_lds16((g1), (dst) + 8192); \
  } while (0)

#define STAGE6(base, ko)                                            \
  do {                                                              \
    STAGE2(gA0 + (ko), gA1 + (ko), (base) + 0 + wid * 1024);        \
    STAGE2(gB00 + (ko), gB01 + (ko), (base) + 16384 + wid * 1024);  \
    STAGE2(gB10 + (ko), gB11 + (ko), (base) + 32768 + wid * 1024);  \
  } while (0)

__global__ void __launch_bounds__(512, 2) gemm_pipe(
    const unsigned short* __restrict__ Xb,   // [M, K] bf16
    const unsigned short* __restrict__ Wb,   // [N, K] bf16
    const float* __restrict__ scale,         // [N]
    const float* __restrict__ bias,          // [N]
    float* __restrict__ out) {               // [M, N] fp32
  __shared__ __align__(16) char lds[147456];  // 3 x 48KB; epilogue reuses [0,128K)

  const int tid = threadIdx.x;
  const int lane = tid & 63;
  const int wid = tid >> 6;   // 0..7
  const int s = wid & 3;      // N-strip (64 cols)
  const int h = wid >> 2;     // K-half (32 of each BK=64)
  const int fr = lane & 15;
  const int fq = lane >> 4;

  // T1: XCD-aware swizzle (688 % 8 == 0 -> bijective). Consecutive wg share bn.
  const int bid = blockIdx.x;
  const int wg = (bid & 7) * (GRID / 8) + (bid >> 3);
  const int bm = wg & 15;
  const int bn = wg >> 4;

  // staging source (inverse-swizzled): thread covers row=tid>>3 (+64), col16=(tid&7)^(row&7)
  const int srow = tid >> 3;
  const int scol = ((tid & 7) ^ (srow & 7)) * 8;  // elements
  const unsigned short* gA0 = Xb + (size_t)(bm * BM + srow) * K_DIM + scol;
  const unsigned short* gA1 = gA0 + (size_t)64 * K_DIM;
  const unsigned short* gB00 = Wb + (size_t)(bn * BN + srow) * K_DIM + scol;
  const unsigned short* gB01 = gB00 + (size_t)64 * K_DIM;
  const unsigned short* gB10 = Wb + (size_t)(bn * BN + 128 + srow) * K_DIM + scol;
  const unsigned short* gB11 = gB10 + (size_t)64 * K_DIM;

  // ds_read offsets (swizzled): byte col = (h*64 + fq*16) ^ ((row&7)<<4), row&7 == lane&7
  const int swz = (lane & 7) << 4;
  const int cb = ((h * 64) + (fq * 16)) ^ swz;
  const int boff = 16384 + ((s >> 1) * 16384);     // Blo or Bhi region
  const int brow = ((s & 1) * 64) * 128;           // + (j*16+fr)*128

  char* const buf0 = lds;
  char* const buf1 = lds + 49152;
  char* const buf2 = lds + 98304;

  // ---- prologue: stage tiles 0,1; publish; read tile0 frags; C0(0)
  STAGE6(buf0, 0);
  STAGE6(buf1, BK);
  VMCNT0();
  BARRIER();

  f32x4 acc[8][4] = {};
  bf16x8 a0[4], a1[4], b[4];
#pragma unroll
  for (int m = 0; m < 4; ++m)
    a0[m] = *(const bf16x8*)(buf0 + (m * 16 + fr) * 128 + cb);
#pragma unroll
  for (int j = 0; j < 4; ++j)
    b[j] = *(const bf16x8*)(buf0 + boff + brow + (j * 16 + fr) * 128 + cb);
#pragma unroll
  for (int m = 0; m < 4; ++m)
    a1[m] = *(const bf16x8*)(buf0 + 8192 + (m * 16 + fr) * 128 + cb);
  __builtin_amdgcn_s_setprio(1);
#pragma unroll
  for (int m = 0; m < 4; ++m)
#pragma unroll
    for (int j = 0; j < 4; ++j)
      acc[m][j] = __builtin_amdgcn_mfma_f32_16x16x32_bf16(a0[m], b[j], acc[m][j], 0, 0, 0);
  __builtin_amdgcn_s_setprio(0);

  char* bc = buf0;    // tile t
  char* bnx = buf1;   // tile t+1 (read target)
  char* bnn = buf2;   // tile t+2 (staging target)

#pragma unroll 1
  for (int t = 0; t < NT; ++t) {
    VMCNT0();    // waits S(t+1), issued one full iteration ago; t=0: no-op
    BARRIER();   // publish S(t+1); all reads of buf (t-1)%3 already drained per-wave
    if (t + 2 < NT) STAGE6(bnn, (t + 2) * BK);
    if (t + 1 < NT) {
#pragma unroll
      for (int m = 0; m < 4; ++m)
        a0[m] = *(const bf16x8*)(bnx + (m * 16 + fr) * 128 + cb);
    }
    // C1(t): a1(t) x b(t)  [lgkmcnt(4) — a0(t+1) stays pending]
    __builtin_amdgcn_s_setprio(1);
#pragma unroll
    for (int m = 0; m < 4; ++m)
#pragma unroll
      for (int j = 0; j < 4; ++j)
        acc[m + 4][j] = __builtin_amdgcn_mfma_f32_16x16x32_bf16(a1[m], b[j], acc[m + 4][j], 0, 0, 0);
    __builtin_amdgcn_s_setprio(0);
    if (t + 1 < NT) {
#pragma unroll
      for (int j = 0; j < 4; ++j)
        b[j] = *(const bf16x8*)(bnx + boff + brow + (j * 16 + fr) * 128 + cb);
#pragma unroll
      for (int m = 0; m < 4; ++m)
        a1[m] = *(const bf16x8*)(bnx + 8192 + (m * 16 + fr) * 128 + cb);
      // C0(t+1): a0(t+1) x b(t+1)  [lgkmcnt(4) — a1(t+1) stays pending]
      __builtin_amdgcn_s_setprio(1);
#pragma unroll
      for (int m = 0; m < 4; ++m)
#pragma unroll
        for (int j = 0; j < 4; ++j)
          acc[m][j] = __builtin_amdgcn_mfma_f32_16x16x32_bf16(a0[m], b[j], acc[m][j], 0, 0, 0);
      __builtin_amdgcn_s_setprio(0);
    }
    char* tmp = bc; bc = bnx; bnx = bnn; bnn = tmp;
  }

  // ---- epilogue: reduce K-half pairs via LDS (fq-XOR swizzle -> 2-way, free),
  // then scale/bias + store. C/D frag: col=j*16+fr, row=m*16+fq*4+jj.
  BARRIER();
  if (h == 1) {
    float* red = (float*)(lds + s * 32768);  // [128][64] f32 per strip
#pragma unroll
    for (int m = 0; m < 8; ++m)
#pragma unroll
      for (int j = 0; j < 4; ++j)
#pragma unroll
        for (int jj = 0; jj < 4; ++jj)
          red[(m * 16 + fq * 4 + jj) * 64 + ((j * 16 + fr) ^ (fq << 4))] = acc[m][j][jj];
  }
  BARRIER();
  if (h == 0) {
    const float* red = (const float*)(lds + s * 32768);
#pragma unroll
    for (int j = 0; j < 4; ++j) {
      const int c = bn * BN + s * 64 + j * 16 + fr;
      const float sc = scale[c];
      const float bi = bias[c];
#pragma unroll
      for (int m = 0; m < 8; ++m) {
        const int r0 = bm * BM + m * 16 + fq * 4;
#pragma unroll
        for (int jj = 0; jj < 4; ++jj) {
          const float v = acc[m][j][jj] +
                          red[(m * 16 + fq * 4 + jj) * 64 + ((j * 16 + fr) ^ (fq << 4))];
          out[(size_t)(r0 + jj) * N_DIM + c] = v * sc + bi;
        }
      }
    }
  }
}

// ---------------- fallback (only if d_ws too small) ----------------

__global__ void __launch_bounds__(256) naive_kernel(
    const float* __restrict__ x, const int* __restrict__ w,
    const float* __restrict__ scale, const float* __restrict__ bias,
    float* __restrict__ out) {
  size_t idx = (size_t)blockIdx.x * 256 + threadIdx.x;
  if (idx >= (size_t)M_DIM * N_DIM) return;
  int m = (int)(idx / N_DIM);
  int n = (int)(idx % N_DIM);
  const float* xr = x + (size_t)m * K_DIM;
  const int* wr = w + (size_t)n * K_DIM;
  float acc = 0.f;
  for (int k = 0; k < K_DIM; k += 4) {
    f4 xv = *(const f4*)(xr + k);
    i4 wv = *(const i4*)(wr + k);
    acc += xv[0] * (float)wv[0];
    acc += xv[1] * (float)wv[1];
    acc += xv[2] * (float)wv[2];
    acc += xv[3] * (float)wv[3];
  }
  out[idx] = acc * scale[n] + bias[n];
}

// ---------------- launch ----------------

extern "C" void kernel_launch(void* const* d_in, const int* in_sizes, int n_in,
                              void* d_out, int out_size, void* d_ws, size_t ws_size,
                              hipStream_t stream) {
  const float* x = (const float*)d_in[0];
  const int* wq = (const int*)d_in[1];
  const float* scale = (const float*)d_in[2];
  const float* bias = (const float*)d_in[3];
  float* out = (float*)d_out;

  const size_t xb_bytes = (size_t)M_DIM * K_DIM * 2;   // 16.8 MB
  const size_t wb_bytes = (size_t)N_DIM * K_DIM * 2;   // 90.2 MB

  if (ws_size >= xb_bytes + wb_bytes) {
    unsigned short* xb = (unsigned short*)d_ws;
    unsigned short* wb = (unsigned short*)((char*)d_ws + xb_bytes);

    const int n8 = M_DIM * K_DIM / 8;
    cvt_x_kernel<<<(n8 + 255) / 256, 256, 0, stream>>>(x, (us8*)xb, n8);

    const int n16 = N_DIM * K_DIM / 16;
    cvt_w_kernel<<<(n16 + 255) / 256, 256, 0, stream>>>(wq, (us8*)wb, n16);

    gemm_pipe<<<GRID, 512, 0, stream>>>(xb, wb, scale, bias, out);
  } else {
    const size_t total = (size_t)M_DIM * N_DIM;
    naive_kernel<<<(unsigned)((total + 255) / 256), 256, 0, stream>>>(x, wq, scale, bias, out);
  }
}

// Round 7
// 250.975 us; speedup vs baseline: 1.0627x; 1.0627x over previous
//
#include <hip/hip_runtime.h>
#include <stdint.h>
#include <stddef.h>

#define M_DIM 2048
#define N_DIM 11008
#define K_DIM 4096
#define BM 128
#define BN 128
#define BK 64
#define NT (K_DIM / BK)   // 64
#define NBM (M_DIM / BM)  // 16
#define NBN (N_DIM / BN)  // 86
#define GRID (NBM * NBN)  // 1376 (divisible by 8 -> XCD swizzle bijective)

typedef __attribute__((ext_vector_type(4))) float f32x4;
typedef __attribute__((ext_vector_type(4))) float f4;
typedef __attribute__((ext_vector_type(4))) int i4;
typedef __attribute__((ext_vector_type(8))) __bf16 bf16x8;
typedef __attribute__((ext_vector_type(8))) unsigned short us8;

#define VMCNT0() asm volatile("s_waitcnt vmcnt(0)" ::: "memory")
#define FENCE() asm volatile("" ::: "memory")
#define BARRIER()                 \
  do {                            \
    FENCE();                      \
    __builtin_amdgcn_s_barrier(); \
    FENCE();                      \
  } while (0)

// round-to-nearest-even fp32 -> bf16
__device__ inline unsigned short f2bf(float f) {
  unsigned u = __builtin_bit_cast(unsigned, f);
  u += 0x7fffu + ((u >> 16) & 1u);
  return (unsigned short)(u >> 16);
}

__device__ inline void gload_lds16(const void* g, void* l) {
  __builtin_amdgcn_global_load_lds((const __attribute__((address_space(1))) void*)g,
                                   (__attribute__((address_space(3))) void*)l, 16, 0, 0);
}

// ---------------- conversion kernels ----------------

__global__ void __launch_bounds__(256) cvt_x_kernel(const float* __restrict__ x,
                                                    us8* __restrict__ xb, int n8) {
  int i = blockIdx.x * 256 + threadIdx.x;
  if (i >= n8) return;
  const f4* src = (const f4*)x;
  f4 a = src[2 * i];
  f4 b = src[2 * i + 1];
  us8 o;
  o[0] = f2bf(a[0]); o[1] = f2bf(a[1]); o[2] = f2bf(a[2]); o[3] = f2bf(a[3]);
  o[4] = f2bf(b[0]); o[5] = f2bf(b[1]); o[6] = f2bf(b[2]); o[7] = f2bf(b[3]);
  xb[i] = o;
}

// W_q arrives as int32 per element; int8-range values are exact in bf16.
__global__ void __launch_bounds__(256) cvt_w_kernel(const int* __restrict__ w,
                                                    us8* __restrict__ wb, int n16) {
  int i = blockIdx.x * 256 + threadIdx.x;
  if (i >= n16) return;
  const i4* src = (const i4*)w + 4 * (size_t)i;
  i4 v0 = src[0], v1 = src[1], v2 = src[2], v3 = src[3];
  us8 lo, hi;
  lo[0] = f2bf((float)v0[0]); lo[1] = f2bf((float)v0[1]);
  lo[2] = f2bf((float)v0[2]); lo[3] = f2bf((float)v0[3]);
  lo[4] = f2bf((float)v1[0]); lo[5] = f2bf((float)v1[1]);
  lo[6] = f2bf((float)v1[2]); lo[7] = f2bf((float)v1[3]);
  hi[0] = f2bf((float)v2[0]); hi[1] = f2bf((float)v2[1]);
  hi[2] = f2bf((float)v2[2]); hi[3] = f2bf((float)v2[3]);
  hi[4] = f2bf((float)v3[0]); hi[5] = f2bf((float)v3[1]);
  hi[6] = f2bf((float)v3[2]); hi[7] = f2bf((float)v3[3]);
  wb[2 * (size_t)i] = lo;
  wb[2 * (size_t)i + 1] = hi;
}

// ------- 2-blocks/CU GEMM: 128x128 tile, BK=64, 4 waves, 64KB LDS double-buffer -------
// 4 waves = 2 N-strips (64 cols) x 2 K-halves (32 of BK=64); wave-tile 128x64 over K=32.
// Per wave per tile: 12 ds_read_b128 (a 8, b 4), 32 MFMA 16x16x32.
// LDS: 2 bufs x 32KB {A[128][64]@0, B[128][64]@16K}; epilogue reduce reuses 64KB.
// Iter t: vmcnt(0) [stage(t) issued at t-1 -> 1 iter slack]; barrier [publish buf d;
//   prior readers of buf d^1 lgkm-drained before their MFMAs pre-barrier]; STAGE8(t+1)
//   -> buf d^1; read a0..3,b; 16 MFMA; read a4..7; 16 MFMA.
// Phase overlap comes from the CO-RESIDENT SECOND BLOCK (independent barriers) filling
// the opposite pipe (m114 MFMA||VALU co-scheduling), not from intra-block skew.
// XOR swizzle both-sides: staged src granule = (tid&7)^(srow&7); read col ^= (row&7)<<4.

#define STAGE8(base, gA, gB, ko)                                          \
  do {                                                                    \
    const int _ko = (ko);                                                 \
    gload_lds16((gA) + _ko, (base) + wid * 1024);                         \
    gload_lds16((gA) + (size_t)32 * K_DIM + _ko, (base) + 4096 + wid * 1024);   \
    gload_lds16((gA) + (size_t)64 * K_DIM + _ko, (base) + 8192 + wid * 1024);   \
    gload_lds16((gA) + (size_t)96 * K_DIM + _ko, (base) + 12288 + wid * 1024);  \
    gload_lds16((gB) + _ko, (base) + 16384 + wid * 1024);                 \
    gload_lds16((gB) + (size_t)32 * K_DIM + _ko, (base) + 20480 + wid * 1024);  \
    gload_lds16((gB) + (size_t)64 * K_DIM + _ko, (base) + 24576 + wid * 1024);  \
    gload_lds16((gB) + (size_t)96 * K_DIM + _ko, (base) + 28672 + wid * 1024);  \
  } while (0)

__global__ void __launch_bounds__(256, 2) gemm_pipe(
    const unsigned short* __restrict__ Xb,   // [M, K] bf16
    const unsigned short* __restrict__ Wb,   // [N, K] bf16
    const float* __restrict__ scale,         // [N]
    const float* __restrict__ bias,          // [N]
    float* __restrict__ out) {               // [M, N] fp32
  __shared__ __align__(16) char lds[65536];  // 2 x 32KB; epilogue reuses all 64KB

  const int tid = threadIdx.x;
  const int lane = tid & 63;
  const int wid = tid >> 6;   // 0..3
  const int s = wid & 1;      // N-strip (64 cols)
  const int h = wid >> 1;     // K-half (32 of BK=64)
  const int fr = lane & 15;
  const int fq = lane >> 4;

  // T1: XCD-aware swizzle (1376 % 8 == 0 -> bijective). Consecutive wg share bn
  // (16 bm-blocks per B-panel stay on one XCD's L2).
  const int bid = blockIdx.x;
  const int wg = (bid & 7) * (GRID / 8) + (bid >> 3);
  const int bm = wg & 15;
  const int bn = wg >> 4;

  // staging source (inverse-swizzled): row=tid>>3 (+32*i), granule=(tid&7)^(row&7)
  const int srow = tid >> 3;
  const int scol = ((tid & 7) ^ (srow & 7)) * 8;  // elements
  const unsigned short* gA = Xb + (size_t)(bm * BM + srow) * K_DIM + scol;
  const unsigned short* gB = Wb + (size_t)(bn * BN + srow) * K_DIM + scol;

  // ds_read offsets (swizzled): byte col = (h*64 + fq*16) ^ ((row&7)<<4); row&7 == lane&7
  const int swz = (lane & 7) << 4;
  const int cb = ((h * 64) + (fq * 16)) ^ swz;
  const int brow = (s * 64) * 128;  // + (j*16+fr)*128 within B region

  char* const buf0 = lds;
  char* const buf1 = lds + 32768;

  // ---- prologue: stage tile 0 only
  STAGE8(buf0, gA, gB, 0);

  f32x4 acc[8][4] = {};

#pragma unroll 1
  for (int t = 0; t < NT; ++t) {
    char* const bc = (t & 1) ? buf1 : buf0;
    char* const bo = (t & 1) ? buf0 : buf1;
    VMCNT0();    // stage(t) complete (issued iter t-1 after barrier; ~1 iter slack)
    BARRIER();   // publish buf bc; prior readers of bo drained pre-barrier
    if (t + 1 < NT) STAGE8(bo, gA, gB, (t + 1) * BK);

    bf16x8 a0[4], b[4], a1[4];
#pragma unroll
    for (int m = 0; m < 4; ++m)
      a0[m] = *(const bf16x8*)(bc + (m * 16 + fr) * 128 + cb);
#pragma unroll
    for (int j = 0; j < 4; ++j)
      b[j] = *(const bf16x8*)(bc + 16384 + brow + (j * 16 + fr) * 128 + cb);
    __builtin_amdgcn_s_setprio(1);
#pragma unroll
    for (int m = 0; m < 4; ++m)
#pragma unroll
      for (int j = 0; j < 4; ++j)
        acc[m][j] = __builtin_amdgcn_mfma_f32_16x16x32_bf16(a0[m], b[j], acc[m][j], 0, 0, 0);
    __builtin_amdgcn_s_setprio(0);
#pragma unroll
    for (int m = 0; m < 4; ++m)
      a1[m] = *(const bf16x8*)(bc + ((m + 4) * 16 + fr) * 128 + cb);
    __builtin_amdgcn_s_setprio(1);
#pragma unroll
    for (int m = 0; m < 4; ++m)
#pragma unroll
      for (int j = 0; j < 4; ++j)
        acc[m + 4][j] = __builtin_amdgcn_mfma_f32_16x16x32_bf16(a1[m], b[j], acc[m + 4][j], 0, 0, 0);
    __builtin_amdgcn_s_setprio(0);
  }

  // ---- epilogue: reduce K-half pairs via LDS (fq-XOR swizzle -> 2-way, free),
  // then scale/bias + store. C/D frag: col=j*16+fr, row=m*16+fq*4+jj.
  BARRIER();
  if (h == 1) {
    float* red = (float*)(lds + s * 32768);  // [128][64] f32 per strip
#pragma unroll
    for (int m = 0; m < 8; ++m)
#pragma unroll
      for (int j = 0; j < 4; ++j)
#pragma unroll
        for (int jj = 0; jj < 4; ++jj)
          red[(m * 16 + fq * 4 + jj) * 64 + ((j * 16 + fr) ^ (fq << 4))] = acc[m][j][jj];
  }
  BARRIER();
  if (h == 0) {
    const float* red = (const float*)(lds + s * 32768);
#pragma unroll
    for (int j = 0; j < 4; ++j) {
      const int c = bn * BN + s * 64 + j * 16 + fr;
      const float sc = scale[c];
      const float bi = bias[c];
#pragma unroll
      for (int m = 0; m < 8; ++m) {
        const int r0 = bm * BM + m * 16 + fq * 4;
#pragma unroll
        for (int jj = 0; jj < 4; ++jj) {
          const float v = acc[m][j][jj] +
                          red[(m * 16 + fq * 4 + jj) * 64 + ((j * 16 + fr) ^ (fq << 4))];
          out[(size_t)(r0 + jj) * N_DIM + c] = v * sc + bi;
        }
      }
    }
  }
}

// ---------------- fallback (only if d_ws too small) ----------------

__global__ void __launch_bounds__(256) naive_kernel(
    const float* __restrict__ x, const int* __restrict__ w,
    const float* __restrict__ scale, const float* __restrict__ bias,
    float* __restrict__ out) {
  size_t idx = (size_t)blockIdx.x * 256 + threadIdx.x;
  if (idx >= (size_t)M_DIM * N_DIM) return;
  int m = (int)(idx / N_DIM);
  int n = (int)(idx % N_DIM);
  const float* xr = x + (size_t)m * K_DIM;
  const int* wr = w + (size_t)n * K_DIM;
  float acc = 0.f;
  for (int k = 0; k < K_DIM; k += 4) {
    f4 xv = *(const f4*)(xr + k);
    i4 wv = *(const i4*)(wr + k);
    acc += xv[0] * (float)wv[0];
    acc += xv[1] * (float)wv[1];
    acc += xv[2] * (float)wv[2];
    acc += xv[3] * (float)wv[3];
  }
  out[idx] = acc * scale[n] + bias[n];
}

// ---------------- launch ----------------

extern "C" void kernel_launch(void* const* d_in, const int* in_sizes, int n_in,
                              void* d_out, int out_size, void* d_ws, size_t ws_size,
                              hipStream_t stream) {
  const float* x = (const float*)d_in[0];
  const int* wq = (const int*)d_in[1];
  const float* scale = (const float*)d_in[2];
  const float* bias = (const float*)d_in[3];
  float* out = (float*)d_out;

  const size_t xb_bytes = (size_t)M_DIM * K_DIM * 2;   // 16.8 MB
  const size_t wb_bytes = (size_t)N_DIM * K_DIM * 2;   // 90.2 MB

  if (ws_size >= xb_bytes + wb_bytes) {
    unsigned short* xb = (unsigned short*)d_ws;
    unsigned short* wb = (unsigned short*)((char*)d_ws + xb_bytes);

    const int n8 = M_DIM * K_DIM / 8;
    cvt_x_kernel<<<(n8 + 255) / 256, 256, 0, stream>>>(x, (us8*)xb, n8);

    const int n16 = N_DIM * K_DIM / 16;
    cvt_w_kernel<<<(n16 + 255) / 256, 256, 0, stream>>>(wq, (us8*)wb, n16);

    gemm_pipe<<<GRID, 256, 0, stream>>>(xb, wb, scale, bias, out);
  } else {
    const size_t total = (size_t)M_DIM * N_DIM;
    naive_kernel<<<(unsigned)((total + 255) / 256), 256, 0, stream>>>(x, wq, scale, bias, out);
  }
}